// Round 19
// baseline (295.517 us; speedup 1.0000x reference)
//
#include <hip/hip_runtime.h>
#include <hip/hip_bf16.h>

// RGCN 2-layer forward. Transform-then-aggregate on BOTH layers.
// L1: Y[n,0:1152] = bf16(x[n]) @ [W_r0..W_r7 | Wroot]  (dense bf16 MFMA GEMM,
//     operand-swapped). Grid (nodeblk, 3 col-panels); 4 waves x 96 cols each;
//     W hi+lo TRIPLE-buffered (2-kstep lead) from L2-resident Wt.
// Sort: counting sort -> ei2[pos] = {src*8+rel, bits(1/cnt)} (mean folded/edge).
// hgather: per-node flat edge loop, 4-deep unrolled; fused layer-2 transform.
// out2: 8 lanes/node (lane=relation), scale pre-folded.

#define NR 8
#define DH 128

typedef short short8 __attribute__((ext_vector_type(8)));
typedef float f32x4 __attribute__((ext_vector_type(4)));

__device__ inline ushort f2bf(float v) {
  __hip_bfloat16 b = __float2bfloat16(v);
  return *reinterpret_cast<ushort*>(&b);
}
__device__ inline float bf2f(ushort u) {
  __hip_bfloat16 b;
  *reinterpret_cast<ushort*>(&b) = u;
  return __bfloat162float(b);
}
__device__ inline uint pk2(float lo, float hi) {
  return (uint)f2bf(lo) | ((uint)f2bf(hi) << 16);
}
union U128 { uint4 u; short8 s; };
union FU { float f; int i; };

// ---------- counting sort ----------
__global__ __launch_bounds__(256) void k_hist(const int* __restrict__ dst, const int* __restrict__ et,
                                              int* __restrict__ hist, int E) {
  int e = blockIdx.x * 256 + threadIdx.x;
  if (e < E) atomicAdd(&hist[dst[e] * NR + et[e]], 1);
}

__global__ __launch_bounds__(256) void k_scan_local(const int* __restrict__ hist, int* __restrict__ offs,
                                                    int* __restrict__ blksum, int S) {
  __shared__ int tsum[256];
  int tid = threadIdx.x;
  int base = blockIdx.x * 1024 + tid * 4;
  int v[4], tot = 0;
  #pragma unroll
  for (int i = 0; i < 4; i++) { v[i] = (base + i < S) ? hist[base + i] : 0; tot += v[i]; }
  tsum[tid] = tot;
  __syncthreads();
  for (int off = 1; off < 256; off <<= 1) {
    int val = tsum[tid];
    int add = (tid >= off) ? tsum[tid - off] : 0;
    __syncthreads();
    tsum[tid] = val + add;
    __syncthreads();
  }
  int run = tsum[tid] - tot;
  #pragma unroll
  for (int i = 0; i < 4; i++) {
    if (base + i < S) offs[base + i] = run;
    run += v[i];
  }
  if (tid == 255) blksum[blockIdx.x] = tsum[255];
}

__global__ __launch_bounds__(512) void k_scan_blk(const int* __restrict__ blksum, int* __restrict__ blkoff, int NB) {
  __shared__ int s[512];
  int tid = threadIdx.x;
  int v = (tid < NB) ? blksum[tid] : 0;
  s[tid] = v;
  __syncthreads();
  for (int off = 1; off < 512; off <<= 1) {
    int val = s[tid];
    int add = (tid >= off) ? s[tid - off] : 0;
    __syncthreads();
    s[tid] = val + add;
    __syncthreads();
  }
  if (tid < NB) blkoff[tid] = s[tid] - v;
}

__global__ __launch_bounds__(256) void k_scan_add(int* __restrict__ offs, const int* __restrict__ blkoff, int S) {
  int tid = threadIdx.x;
  int base = blockIdx.x * 1024 + tid * 4;
  int add = blkoff[blockIdx.x];
  #pragma unroll
  for (int i = 0; i < 4; i++)
    if (base + i < S) offs[base + i] += add;
}

// scatter: ei2[pos] = {src*8+rel, bits(1/cnt)}; offs[seg] becomes segment END
__global__ __launch_bounds__(256) void k_scatter_idx(const int* __restrict__ src, const int* __restrict__ dst,
                                                     const int* __restrict__ et, const int* __restrict__ hist,
                                                     int* __restrict__ offs, int2* __restrict__ ei2, int E) {
  int e = blockIdx.x * 256 + threadIdx.x;
  if (e >= E) return;
  int r = et[e];
  int seg = dst[e] * NR + r;
  int pos = atomicAdd(&offs[seg], 1);
  FU sc;
  sc.f = 1.f / fmaxf((float)hist[seg], 1.f);
  ei2[pos] = make_int2(src[e] * NR + r, sc.i);
}

// ---------- W split+transpose: Wt[c][k], c in [0,1152), k in [0,128) ----------
__global__ __launch_bounds__(128) void k_wsplit(const float* __restrict__ W1, const float* __restrict__ Wr1,
                                                ushort* __restrict__ WtH, ushort* __restrict__ WtL) {
  int c = blockIdx.x;          // 0..1151
  int k = threadIdx.x;         // 0..127
  float v;
  if (c < 1024) {
    int r = c >> 7, col = c & 127;
    v = W1[((size_t)r * 128 + k) * 128 + col];
  } else {
    v = Wr1[(size_t)k * 128 + (c - 1024)];
  }
  ushort hi = f2bf(v);
  ushort lo = f2bf(v - bf2f(hi));
  WtH[(size_t)c * 128 + k] = hi;
  WtL[(size_t)c * 128 + k] = lo;
}

// ---------- dense GEMM: Y[N,1152] = bf16(x[N,128]) @ Wt^T, bf16 out ----------
// Operand swap: D = mfma(A=Wfrag, B=xfrag) -> D[row=Y-col][col=node].
// Grid (ceil(N/64), 3): blockIdx.y = 384-col panel; 4 waves x 96 cols (3 chunks).
// x cast f32->bf16 in prologue into xbr[4][4] (register-resident).
// W hi+lo TRIPLE-buffered (pw0/1/2, 2-kstep lead). Barrier-free, no LDS, rule #20.
__global__ __launch_bounds__(256) void k_gemm_dense(
    const float* __restrict__ x,
    const ushort* __restrict__ WtH, const ushort* __restrict__ WtL,
    ushort* __restrict__ Y, int N) {
  int tid = threadIdx.x;
  int w = tid >> 6, lane = tid & 63;
  int n0 = blockIdx.x * 64;
  int wbase = blockIdx.y * 384 + w * 96;

  int frow = lane & 15;
  int fk8 = (lane >> 4) * 8;
  int q4 = (lane >> 4) * 4;

  int anode[4];
  bool nodeok[4];
  size_t ybase[4];
  #pragma unroll
  for (int nf = 0; nf < 4; nf++) {
    int n = n0 + nf * 16 + frow;
    nodeok[nf] = (n < N);
    anode[nf] = nodeok[nf] ? n : (N - 1);
    ybase[nf] = (size_t)anode[nf] * 1152 + q4;
  }

  uint4 xbr[4][4];
  #pragma unroll
  for (int nf = 0; nf < 4; nf++) {
    #pragma unroll
    for (int kc = 0; kc < 4; kc++) {
      const float4* xp = (const float4*)(x + (size_t)anode[nf] * 128 + kc * 32 + fk8);
      float4 v0 = xp[0], v1 = xp[1];
      uint4 o;
      o.x = pk2(v0.x, v0.y);
      o.y = pk2(v0.z, v0.w);
      o.z = pk2(v1.x, v1.y);
      o.w = pk2(v1.z, v1.w);
      xbr[nf][kc] = o;
    }
  }

  f32x4 acc[2][4];
  uint4 pw0[2][2], pw1[2][2], pw2[2][2];  // W frags [cf][plane], triple-buffered

  #define LOADW(P, CB, KC)                                                     \
    {                                                                          \
      _Pragma("unroll")                                                        \
      for (int cf = 0; cf < 2; cf++) {                                         \
        int c_ = (CB) + cf * 16 + frow;                                        \
        P[cf][0] = *(const uint4*)(WtH + (size_t)c_ * 128 + (KC) * 32 + fk8);  \
        P[cf][1] = *(const uint4*)(WtL + (size_t)c_ * 128 + (KC) * 32 + fk8);  \
      }                                                                        \
    }
  #define KSTEP(KC, PWU)                                                       \
    {                                                                          \
      _Pragma("unroll")                                                        \
      for (int cf = 0; cf < 2; cf++) {                                         \
        U128 wh_, wl_;                                                         \
        wh_.u = PWU[cf][0];                                                    \
        wl_.u = PWU[cf][1];                                                    \
        _Pragma("unroll")                                                      \
        for (int nf = 0; nf < 4; nf++) {                                       \
          U128 xv_;                                                            \
          xv_.u = xbr[nf][KC];                                                 \
          acc[cf][nf] = __builtin_amdgcn_mfma_f32_16x16x32_bf16(wh_.s, xv_.s, acc[cf][nf], 0, 0, 0); \
          acc[cf][nf] = __builtin_amdgcn_mfma_f32_16x16x32_bf16(wl_.s, xv_.s, acc[cf][nf], 0, 0, 0); \
        }                                                                      \
      }                                                                        \
    }
  // Entry invariant: X0 = CB.k0, X1 = CB.k1 already loaded (2-kstep lead).
  #define CHUNK(CB, NCB, X0, X1, X2, ISLAST)                                   \
    {                                                                          \
      _Pragma("unroll")                                                        \
      for (int cf = 0; cf < 2; cf++)                                           \
        _Pragma("unroll")                                                      \
        for (int nf = 0; nf < 4; nf++) acc[cf][nf] = (f32x4){0.f, 0.f, 0.f, 0.f}; \
      LOADW(X2, CB, 2);                                                        \
      KSTEP(0, X0);                                                            \
      LOADW(X0, CB, 3);                                                        \
      KSTEP(1, X1);                                                            \
      if (!(ISLAST)) { LOADW(X1, NCB, 0); }                                    \
      KSTEP(2, X2);                                                            \
      if (!(ISLAST)) { LOADW(X2, NCB, 1); }                                    \
      KSTEP(3, X0);                                                            \
      _Pragma("unroll")                                                        \
      for (int cf = 0; cf < 2; cf++)                                           \
        _Pragma("unroll")                                                      \
        for (int nf = 0; nf < 4; nf++) {                                       \
          if (nodeok[nf]) {                                                    \
            ushort4 o_;                                                        \
            o_.x = f2bf(acc[cf][nf][0]);                                       \
            o_.y = f2bf(acc[cf][nf][1]);                                       \
            o_.z = f2bf(acc[cf][nf][2]);                                       \
            o_.w = f2bf(acc[cf][nf][3]);                                       \
            *(ushort4*)(Y + ybase[nf] + (CB) + cf * 16) = o_;                  \
          }                                                                    \
        }                                                                      \
    }

  LOADW(pw0, wbase, 0);
  LOADW(pw1, wbase, 1);

  CHUNK(wbase + 0,  wbase + 32, pw0, pw1, pw2, 0)
  CHUNK(wbase + 32, wbase + 64, pw1, pw2, pw0, 0)
  CHUNK(wbase + 64, 0,          pw2, pw0, pw1, 1)

  #undef LOADW
  #undef KSTEP
  #undef CHUNK
}

// ---------- fused flat h-gather + layer-2 transform ----------
__global__ __launch_bounds__(256) void k_hgather(const int* __restrict__ offs, const int* __restrict__ hist,
                                                 const int2* __restrict__ ei2, const ushort* __restrict__ Y,
                                                 const float* __restrict__ b1,
                                                 const float* __restrict__ W2, const float* __restrict__ Wr2,
                                                 float* __restrict__ t, int N) {
  __shared__ float Wt[18 * 128];
  int tid = threadIdx.x;
  for (int i = tid; i < 2304; i += 256) {
    float v; int oc, d;
    if (i < 2048) { int r = i >> 8, rem = i & 255; d = rem >> 1; int c = rem & 1; oc = r * 2 + c; v = W2[i]; }
    else { int i2 = i - 2048; d = i2 >> 1; int c = i2 & 1; oc = 16 + c; v = Wr2[i2]; }
    Wt[oc * 128 + d] = v;
  }
  __syncthreads();

  int node = blockIdx.x * 4 + (tid >> 6);
  int lane = tid & 63;
  if (node >= N) return;
  int c0 = lane * 2;
  int seg0 = node * NR;
  int st = offs[seg0] - hist[seg0];
  int en = offs[seg0 + 7];

  uint vroot = *(const uint*)(Y + (size_t)node * 1152 + 1024 + c0);
  float2 bb = *(const float2*)(b1 + c0);
  float ax = bf2f((ushort)(vroot & 0xffff)) + bb.x;
  float ay = bf2f((ushort)(vroot >> 16)) + bb.y;

  int i = st;
  for (; i + 4 <= en; i += 4) {
    int2 e0 = ei2[i + 0];
    int2 e1 = ei2[i + 1];
    int2 e2 = ei2[i + 2];
    int2 e3 = ei2[i + 3];
    uint y0 = ((uint)(e0.x + (e0.x >> 3)) << 7) + c0;
    uint y1 = ((uint)(e1.x + (e1.x >> 3)) << 7) + c0;
    uint y2 = ((uint)(e2.x + (e2.x >> 3)) << 7) + c0;
    uint y3 = ((uint)(e3.x + (e3.x >> 3)) << 7) + c0;
    uint v0 = *(const uint*)(Y + y0);
    uint v1 = *(const uint*)(Y + y1);
    uint v2 = *(const uint*)(Y + y2);
    uint v3 = *(const uint*)(Y + y3);
    FU s0, s1, s2, s3;
    s0.i = e0.y; s1.i = e1.y; s2.i = e2.y; s3.i = e3.y;
    ax += bf2f((ushort)(v0 & 0xffff)) * s0.f + bf2f((ushort)(v1 & 0xffff)) * s1.f +
          bf2f((ushort)(v2 & 0xffff)) * s2.f + bf2f((ushort)(v3 & 0xffff)) * s3.f;
    ay += bf2f((ushort)(v0 >> 16)) * s0.f + bf2f((ushort)(v1 >> 16)) * s1.f +
          bf2f((ushort)(v2 >> 16)) * s2.f + bf2f((ushort)(v3 >> 16)) * s3.f;
  }
  for (; i < en; i++) {
    int2 e = ei2[i];
    uint yo = ((uint)(e.x + (e.x >> 3)) << 7) + c0;
    uint v = *(const uint*)(Y + yo);
    FU sc; sc.i = e.y;
    ax += bf2f((ushort)(v & 0xffff)) * sc.f;
    ay += bf2f((ushort)(v >> 16)) * sc.f;
  }

  float hx = fmaxf(ax, 0.f);
  float hy = fmaxf(ay, 0.f);

  #pragma unroll
  for (int oc = 0; oc < 18; oc++) {
    float2 wv = *(const float2*)(Wt + oc * 128 + c0);
    float p = hx * wv.x + hy * wv.y;
    p += __shfl_xor(p, 32); p += __shfl_xor(p, 16); p += __shfl_xor(p, 8);
    p += __shfl_xor(p, 4);  p += __shfl_xor(p, 2);  p += __shfl_xor(p, 1);
    if (lane == 0) t[(size_t)node * 18 + oc] = p;
  }
}

// ---------- output: 8 lanes per node (lane = relation), scale pre-folded ----------
__global__ __launch_bounds__(256) void k_out2(const int* __restrict__ offs, const int* __restrict__ hist,
                                              const int2* __restrict__ ei2, const float* __restrict__ t,
                                              const float* __restrict__ b2, float* __restrict__ out, int N) {
  int tid = threadIdx.x;
  int node = blockIdx.x * 32 + (tid >> 3);
  int r = tid & 7;
  if (node >= N) return;
  int seg = node * NR + r;
  int en = offs[seg];
  int cc = hist[seg];
  float s0 = 0.f, s1 = 0.f;
  for (int i = en - cc; i < en; i++) {
    int2 e = ei2[i];
    int src = e.x >> 3;
    FU sc; sc.i = e.y;
    float2 tv = *(const float2*)(t + (size_t)src * 18 + r * 2);
    s0 += tv.x * sc.f;
    s1 += tv.y * sc.f;
  }
  s0 += __shfl_xor(s0, 1); s1 += __shfl_xor(s1, 1);
  s0 += __shfl_xor(s0, 2); s1 += __shfl_xor(s1, 2);
  s0 += __shfl_xor(s0, 4); s1 += __shfl_xor(s1, 4);
  if (r == 0) {
    out[(size_t)node * 2 + 0] = s0 + t[(size_t)node * 18 + 16] + b2[0];
    out[(size_t)node * 2 + 1] = s1 + t[(size_t)node * 18 + 17] + b2[1];
  }
}

extern "C" void kernel_launch(void* const* d_in, const int* in_sizes, int n_in,
                              void* d_out, int out_size, void* d_ws, size_t ws_size,
                              hipStream_t stream) {
  const float* x   = (const float*)d_in[0];
  const int*   ei  = (const int*)d_in[1];
  const int*   et  = (const int*)d_in[2];
  const float* W1  = (const float*)d_in[3];
  const float* Wr1 = (const float*)d_in[4];
  const float* b1  = (const float*)d_in[5];
  const float* W2  = (const float*)d_in[6];
  const float* Wr2 = (const float*)d_in[7];
  const float* b2  = (const float*)d_in[8];
  float* out = (float*)d_out;

  int E = in_sizes[1] / 2;
  int N = in_sizes[0] / DH;
  int S = N * NR;
  const int* src = ei;
  const int* dst = ei + E;

  // ws layout: ints | ei2 (int2, E) | WtH WtL | Y (bf16, N*1152) | t
  int* hist       = (int*)d_ws;                  // S
  int* offs       = hist + S;                    // S
  int* blksum     = offs + S;                    // 1024
  int* blkoff     = blksum + 1024;               // 1024
  int2* ei2       = (int2*)(blkoff + 1024);      // E int2 (8B-aligned)
  size_t int_elems = (size_t)S * 2 + 2048 + (size_t)E * 2;
  int_elems = (int_elems + 3) & ~(size_t)3;      // 16B align
  ushort* WtH = (ushort*)(hist + int_elems);     // 1152*128
  ushort* WtL = WtH + 1152 * 128;                // 1152*128
  ushort* Y   = WtL + 1152 * 128;                // N*1152
  size_t ush_elems = 2 * 1152 * 128 + (size_t)N * 1152;
  ush_elems = (ush_elems + 1) & ~(size_t)1;      // float align
  float* t = (float*)(WtH + ush_elems);          // N*18

  hipMemsetAsync(hist, 0, sizeof(int) * (size_t)S, stream);

  k_hist<<<(E + 255) / 256, 256, 0, stream>>>(dst, et, hist, E);

  int NB = (S + 1023) / 1024;
  k_scan_local<<<NB, 256, 0, stream>>>(hist, offs, blksum, S);
  k_scan_blk<<<1, 512, 0, stream>>>(blksum, blkoff, NB);
  k_scan_add<<<NB, 256, 0, stream>>>(offs, blkoff, S);

  k_scatter_idx<<<(E + 255) / 256, 256, 0, stream>>>(src, dst, et, hist, offs, ei2, E);

  k_wsplit<<<1152, 128, 0, stream>>>(W1, Wr1, WtH, WtL);

  k_gemm_dense<<<dim3((N + 63) / 64, 3), 256, 0, stream>>>(x, WtH, WtL, Y, N);

  k_hgather<<<(N + 3) / 4, 256, 0, stream>>>(offs, hist, ei2, Y, b1, W2, Wr2, t, N);

  k_out2<<<(N + 31) / 32, 256, 0, stream>>>(offs, hist, ei2, t, b2, out, N);
}

// Round 20
// 284.770 us; speedup vs baseline: 1.0377x; 1.0377x over previous
//
#include <hip/hip_runtime.h>
#include <hip/hip_bf16.h>

// RGCN 2-layer forward. Transform-then-aggregate on BOTH layers.
// L1: Y[n,0:1152] = bf16(x[n]) @ [W_r0..W_r7 | Wroot]  (dense bf16 MFMA GEMM,
//     operand-swapped). r18 geometry: 782 blocks, 4 waves x 288-col panels,
//     576 MFMA/wave; THIS ROUND: W hi+lo TRIPLE-buffered (2-kstep lead).
// Sort: counting sort -> ei2[pos] = {src*8+rel, bits(1/cnt)} (mean folded/edge).
// hgather: per-node flat edge loop, 4-deep unrolled; fused layer-2 transform.
// out2: 8 lanes/node (lane=relation), scale pre-folded.

#define NR 8
#define DH 128

typedef short short8 __attribute__((ext_vector_type(8)));
typedef float f32x4 __attribute__((ext_vector_type(4)));

__device__ inline ushort f2bf(float v) {
  __hip_bfloat16 b = __float2bfloat16(v);
  return *reinterpret_cast<ushort*>(&b);
}
__device__ inline float bf2f(ushort u) {
  __hip_bfloat16 b;
  *reinterpret_cast<ushort*>(&b) = u;
  return __bfloat162float(b);
}
__device__ inline uint pk2(float lo, float hi) {
  return (uint)f2bf(lo) | ((uint)f2bf(hi) << 16);
}
union U128 { uint4 u; short8 s; };
union FU { float f; int i; };

// ---------- counting sort ----------
__global__ __launch_bounds__(256) void k_hist(const int* __restrict__ dst, const int* __restrict__ et,
                                              int* __restrict__ hist, int E) {
  int e = blockIdx.x * 256 + threadIdx.x;
  if (e < E) atomicAdd(&hist[dst[e] * NR + et[e]], 1);
}

__global__ __launch_bounds__(256) void k_scan_local(const int* __restrict__ hist, int* __restrict__ offs,
                                                    int* __restrict__ blksum, int S) {
  __shared__ int tsum[256];
  int tid = threadIdx.x;
  int base = blockIdx.x * 1024 + tid * 4;
  int v[4], tot = 0;
  #pragma unroll
  for (int i = 0; i < 4; i++) { v[i] = (base + i < S) ? hist[base + i] : 0; tot += v[i]; }
  tsum[tid] = tot;
  __syncthreads();
  for (int off = 1; off < 256; off <<= 1) {
    int val = tsum[tid];
    int add = (tid >= off) ? tsum[tid - off] : 0;
    __syncthreads();
    tsum[tid] = val + add;
    __syncthreads();
  }
  int run = tsum[tid] - tot;
  #pragma unroll
  for (int i = 0; i < 4; i++) {
    if (base + i < S) offs[base + i] = run;
    run += v[i];
  }
  if (tid == 255) blksum[blockIdx.x] = tsum[255];
}

__global__ __launch_bounds__(512) void k_scan_blk(const int* __restrict__ blksum, int* __restrict__ blkoff, int NB) {
  __shared__ int s[512];
  int tid = threadIdx.x;
  int v = (tid < NB) ? blksum[tid] : 0;
  s[tid] = v;
  __syncthreads();
  for (int off = 1; off < 512; off <<= 1) {
    int val = s[tid];
    int add = (tid >= off) ? s[tid - off] : 0;
    __syncthreads();
    s[tid] = val + add;
    __syncthreads();
  }
  if (tid < NB) blkoff[tid] = s[tid] - v;
}

__global__ __launch_bounds__(256) void k_scan_add(int* __restrict__ offs, const int* __restrict__ blkoff, int S) {
  int tid = threadIdx.x;
  int base = blockIdx.x * 1024 + tid * 4;
  int add = blkoff[blockIdx.x];
  #pragma unroll
  for (int i = 0; i < 4; i++)
    if (base + i < S) offs[base + i] += add;
}

// scatter: ei2[pos] = {src*8+rel, bits(1/cnt)}; offs[seg] becomes segment END
__global__ __launch_bounds__(256) void k_scatter_idx(const int* __restrict__ src, const int* __restrict__ dst,
                                                     const int* __restrict__ et, const int* __restrict__ hist,
                                                     int* __restrict__ offs, int2* __restrict__ ei2, int E) {
  int e = blockIdx.x * 256 + threadIdx.x;
  if (e >= E) return;
  int r = et[e];
  int seg = dst[e] * NR + r;
  int pos = atomicAdd(&offs[seg], 1);
  FU sc;
  sc.f = 1.f / fmaxf((float)hist[seg], 1.f);
  ei2[pos] = make_int2(src[e] * NR + r, sc.i);
}

// ---------- W split+transpose: Wt[c][k], c in [0,1152), k in [0,128) ----------
__global__ __launch_bounds__(128) void k_wsplit(const float* __restrict__ W1, const float* __restrict__ Wr1,
                                                ushort* __restrict__ WtH, ushort* __restrict__ WtL) {
  int c = blockIdx.x;          // 0..1151
  int k = threadIdx.x;         // 0..127
  float v;
  if (c < 1024) {
    int r = c >> 7, col = c & 127;
    v = W1[((size_t)r * 128 + k) * 128 + col];
  } else {
    v = Wr1[(size_t)k * 128 + (c - 1024)];
  }
  ushort hi = f2bf(v);
  ushort lo = f2bf(v - bf2f(hi));
  WtH[(size_t)c * 128 + k] = hi;
  WtL[(size_t)c * 128 + k] = lo;
}

// ---------- dense GEMM: Y[N,1152] = bf16(x[N,128]) @ Wt^T, bf16 out ----------
// Operand swap: D = mfma(A=Wfrag, B=xfrag) -> D[row=Y-col][col=node].
// 256 thr = 4 waves; block = 64 nodes; wave w owns C-panel [w*288, +288) (9 chunks).
// x cast f32->bf16 in prologue into xbr[4][4] (register-resident).
// W hi+lo TRIPLE-buffered (pw0/1/2, 2-kstep lead) from L2-resident Wt.
// 576 MFMA/wave; packed ushort4 Y stores. Barrier-free, no LDS, rule #20.
__global__ __launch_bounds__(256) void k_gemm_dense(
    const float* __restrict__ x,
    const ushort* __restrict__ WtH, const ushort* __restrict__ WtL,
    ushort* __restrict__ Y, int N) {
  int tid = threadIdx.x;
  int w = tid >> 6, lane = tid & 63;
  int n0 = blockIdx.x * 64;
  int wbase = w * 288;

  int frow = lane & 15;
  int fk8 = (lane >> 4) * 8;
  int q4 = (lane >> 4) * 4;

  int anode[4];
  bool nodeok[4];
  size_t ybase[4];
  #pragma unroll
  for (int nf = 0; nf < 4; nf++) {
    int n = n0 + nf * 16 + frow;
    nodeok[nf] = (n < N);
    anode[nf] = nodeok[nf] ? n : (N - 1);
    ybase[nf] = (size_t)anode[nf] * 1152 + q4;
  }

  uint4 xbr[4][4];
  #pragma unroll
  for (int nf = 0; nf < 4; nf++) {
    #pragma unroll
    for (int kc = 0; kc < 4; kc++) {
      const float4* xp = (const float4*)(x + (size_t)anode[nf] * 128 + kc * 32 + fk8);
      float4 v0 = xp[0], v1 = xp[1];
      uint4 o;
      o.x = pk2(v0.x, v0.y);
      o.y = pk2(v0.z, v0.w);
      o.z = pk2(v1.x, v1.y);
      o.w = pk2(v1.z, v1.w);
      xbr[nf][kc] = o;
    }
  }

  f32x4 acc[2][4];
  uint4 pw0[2][2], pw1[2][2], pw2[2][2];  // W frags [cf][plane], triple-buffered

  #define LOADW(P, CB, KC)                                                     \
    {                                                                          \
      _Pragma("unroll")                                                        \
      for (int cf = 0; cf < 2; cf++) {                                         \
        int c_ = (CB) + cf * 16 + frow;                                        \
        P[cf][0] = *(const uint4*)(WtH + (size_t)c_ * 128 + (KC) * 32 + fk8);  \
        P[cf][1] = *(const uint4*)(WtL + (size_t)c_ * 128 + (KC) * 32 + fk8);  \
      }                                                                        \
    }
  #define KSTEP(KC, PWU)                                                       \
    {                                                                          \
      _Pragma("unroll")                                                        \
      for (int cf = 0; cf < 2; cf++) {                                         \
        U128 wh_, wl_;                                                         \
        wh_.u = PWU[cf][0];                                                    \
        wl_.u = PWU[cf][1];                                                    \
        _Pragma("unroll")                                                      \
        for (int nf = 0; nf < 4; nf++) {                                       \
          U128 xv_;                                                            \
          xv_.u = xbr[nf][KC];                                                 \
          acc[cf][nf] = __builtin_amdgcn_mfma_f32_16x16x32_bf16(wh_.s, xv_.s, acc[cf][nf], 0, 0, 0); \
          acc[cf][nf] = __builtin_amdgcn_mfma_f32_16x16x32_bf16(wl_.s, xv_.s, acc[cf][nf], 0, 0, 0); \
        }                                                                      \
      }                                                                        \
    }
  // Entry invariant: X0 = CB.k0, X1 = CB.k1 already loaded (2-kstep lead).
  #define CHUNK(CB, NCB, X0, X1, X2, ISLAST)                                   \
    {                                                                          \
      _Pragma("unroll")                                                        \
      for (int cf = 0; cf < 2; cf++)                                           \
        _Pragma("unroll")                                                      \
        for (int nf = 0; nf < 4; nf++) acc[cf][nf] = (f32x4){0.f, 0.f, 0.f, 0.f}; \
      LOADW(X2, CB, 2);                                                        \
      KSTEP(0, X0);                                                            \
      LOADW(X0, CB, 3);                                                        \
      KSTEP(1, X1);                                                            \
      if (!(ISLAST)) { LOADW(X1, NCB, 0); }                                    \
      KSTEP(2, X2);                                                            \
      if (!(ISLAST)) { LOADW(X2, NCB, 1); }                                    \
      KSTEP(3, X0);                                                            \
      _Pragma("unroll")                                                        \
      for (int cf = 0; cf < 2; cf++)                                           \
        _Pragma("unroll")                                                      \
        for (int nf = 0; nf < 4; nf++) {                                       \
          if (nodeok[nf]) {                                                    \
            ushort4 o_;                                                        \
            o_.x = f2bf(acc[cf][nf][0]);                                       \
            o_.y = f2bf(acc[cf][nf][1]);                                       \
            o_.z = f2bf(acc[cf][nf][2]);                                       \
            o_.w = f2bf(acc[cf][nf][3]);                                       \
            *(ushort4*)(Y + ybase[nf] + (CB) + cf * 16) = o_;                  \
          }                                                                    \
        }                                                                      \
    }

  LOADW(pw0, wbase, 0);
  LOADW(pw1, wbase, 1);

  CHUNK(wbase + 0,   wbase + 32,  pw0, pw1, pw2, 0)
  CHUNK(wbase + 32,  wbase + 64,  pw1, pw2, pw0, 0)
  CHUNK(wbase + 64,  wbase + 96,  pw2, pw0, pw1, 0)
  CHUNK(wbase + 96,  wbase + 128, pw0, pw1, pw2, 0)
  CHUNK(wbase + 128, wbase + 160, pw1, pw2, pw0, 0)
  CHUNK(wbase + 160, wbase + 192, pw2, pw0, pw1, 0)
  CHUNK(wbase + 192, wbase + 224, pw0, pw1, pw2, 0)
  CHUNK(wbase + 224, wbase + 256, pw1, pw2, pw0, 0)
  CHUNK(wbase + 256, 0,           pw2, pw0, pw1, 1)

  #undef LOADW
  #undef KSTEP
  #undef CHUNK
}

// ---------- fused flat h-gather + layer-2 transform ----------
__global__ __launch_bounds__(256) void k_hgather(const int* __restrict__ offs, const int* __restrict__ hist,
                                                 const int2* __restrict__ ei2, const ushort* __restrict__ Y,
                                                 const float* __restrict__ b1,
                                                 const float* __restrict__ W2, const float* __restrict__ Wr2,
                                                 float* __restrict__ t, int N) {
  __shared__ float Wt[18 * 128];
  int tid = threadIdx.x;
  for (int i = tid; i < 2304; i += 256) {
    float v; int oc, d;
    if (i < 2048) { int r = i >> 8, rem = i & 255; d = rem >> 1; int c = rem & 1; oc = r * 2 + c; v = W2[i]; }
    else { int i2 = i - 2048; d = i2 >> 1; int c = i2 & 1; oc = 16 + c; v = Wr2[i2]; }
    Wt[oc * 128 + d] = v;
  }
  __syncthreads();

  int node = blockIdx.x * 4 + (tid >> 6);
  int lane = tid & 63;
  if (node >= N) return;
  int c0 = lane * 2;
  int seg0 = node * NR;
  int st = offs[seg0] - hist[seg0];
  int en = offs[seg0 + 7];

  uint vroot = *(const uint*)(Y + (size_t)node * 1152 + 1024 + c0);
  float2 bb = *(const float2*)(b1 + c0);
  float ax = bf2f((ushort)(vroot & 0xffff)) + bb.x;
  float ay = bf2f((ushort)(vroot >> 16)) + bb.y;

  int i = st;
  for (; i + 4 <= en; i += 4) {
    int2 e0 = ei2[i + 0];
    int2 e1 = ei2[i + 1];
    int2 e2 = ei2[i + 2];
    int2 e3 = ei2[i + 3];
    uint y0 = ((uint)(e0.x + (e0.x >> 3)) << 7) + c0;
    uint y1 = ((uint)(e1.x + (e1.x >> 3)) << 7) + c0;
    uint y2 = ((uint)(e2.x + (e2.x >> 3)) << 7) + c0;
    uint y3 = ((uint)(e3.x + (e3.x >> 3)) << 7) + c0;
    uint v0 = *(const uint*)(Y + y0);
    uint v1 = *(const uint*)(Y + y1);
    uint v2 = *(const uint*)(Y + y2);
    uint v3 = *(const uint*)(Y + y3);
    FU s0, s1, s2, s3;
    s0.i = e0.y; s1.i = e1.y; s2.i = e2.y; s3.i = e3.y;
    ax += bf2f((ushort)(v0 & 0xffff)) * s0.f + bf2f((ushort)(v1 & 0xffff)) * s1.f +
          bf2f((ushort)(v2 & 0xffff)) * s2.f + bf2f((ushort)(v3 & 0xffff)) * s3.f;
    ay += bf2f((ushort)(v0 >> 16)) * s0.f + bf2f((ushort)(v1 >> 16)) * s1.f +
          bf2f((ushort)(v2 >> 16)) * s2.f + bf2f((ushort)(v3 >> 16)) * s3.f;
  }
  for (; i < en; i++) {
    int2 e = ei2[i];
    uint yo = ((uint)(e.x + (e.x >> 3)) << 7) + c0;
    uint v = *(const uint*)(Y + yo);
    FU sc; sc.i = e.y;
    ax += bf2f((ushort)(v & 0xffff)) * sc.f;
    ay += bf2f((ushort)(v >> 16)) * sc.f;
  }

  float hx = fmaxf(ax, 0.f);
  float hy = fmaxf(ay, 0.f);

  #pragma unroll
  for (int oc = 0; oc < 18; oc++) {
    float2 wv = *(const float2*)(Wt + oc * 128 + c0);
    float p = hx * wv.x + hy * wv.y;
    p += __shfl_xor(p, 32); p += __shfl_xor(p, 16); p += __shfl_xor(p, 8);
    p += __shfl_xor(p, 4);  p += __shfl_xor(p, 2);  p += __shfl_xor(p, 1);
    if (lane == 0) t[(size_t)node * 18 + oc] = p;
  }
}

// ---------- output: 8 lanes per node (lane = relation), scale pre-folded ----------
__global__ __launch_bounds__(256) void k_out2(const int* __restrict__ offs, const int* __restrict__ hist,
                                              const int2* __restrict__ ei2, const float* __restrict__ t,
                                              const float* __restrict__ b2, float* __restrict__ out, int N) {
  int tid = threadIdx.x;
  int node = blockIdx.x * 32 + (tid >> 3);
  int r = tid & 7;
  if (node >= N) return;
  int seg = node * NR + r;
  int en = offs[seg];
  int cc = hist[seg];
  float s0 = 0.f, s1 = 0.f;
  for (int i = en - cc; i < en; i++) {
    int2 e = ei2[i];
    int src = e.x >> 3;
    FU sc; sc.i = e.y;
    float2 tv = *(const float2*)(t + (size_t)src * 18 + r * 2);
    s0 += tv.x * sc.f;
    s1 += tv.y * sc.f;
  }
  s0 += __shfl_xor(s0, 1); s1 += __shfl_xor(s1, 1);
  s0 += __shfl_xor(s0, 2); s1 += __shfl_xor(s1, 2);
  s0 += __shfl_xor(s0, 4); s1 += __shfl_xor(s1, 4);
  if (r == 0) {
    out[(size_t)node * 2 + 0] = s0 + t[(size_t)node * 18 + 16] + b2[0];
    out[(size_t)node * 2 + 1] = s1 + t[(size_t)node * 18 + 17] + b2[1];
  }
}

extern "C" void kernel_launch(void* const* d_in, const int* in_sizes, int n_in,
                              void* d_out, int out_size, void* d_ws, size_t ws_size,
                              hipStream_t stream) {
  const float* x   = (const float*)d_in[0];
  const int*   ei  = (const int*)d_in[1];
  const int*   et  = (const int*)d_in[2];
  const float* W1  = (const float*)d_in[3];
  const float* Wr1 = (const float*)d_in[4];
  const float* b1  = (const float*)d_in[5];
  const float* W2  = (const float*)d_in[6];
  const float* Wr2 = (const float*)d_in[7];
  const float* b2  = (const float*)d_in[8];
  float* out = (float*)d_out;

  int E = in_sizes[1] / 2;
  int N = in_sizes[0] / DH;
  int S = N * NR;
  const int* src = ei;
  const int* dst = ei + E;

  // ws layout: ints | ei2 (int2, E) | WtH WtL | Y (bf16, N*1152) | t
  int* hist       = (int*)d_ws;                  // S
  int* offs       = hist + S;                    // S
  int* blksum     = offs + S;                    // 1024
  int* blkoff     = blksum + 1024;               // 1024
  int2* ei2       = (int2*)(blkoff + 1024);      // E int2 (8B-aligned)
  size_t int_elems = (size_t)S * 2 + 2048 + (size_t)E * 2;
  int_elems = (int_elems + 3) & ~(size_t)3;      // 16B align
  ushort* WtH = (ushort*)(hist + int_elems);     // 1152*128
  ushort* WtL = WtH + 1152 * 128;                // 1152*128
  ushort* Y   = WtL + 1152 * 128;                // N*1152
  size_t ush_elems = 2 * 1152 * 128 + (size_t)N * 1152;
  ush_elems = (ush_elems + 1) & ~(size_t)1;      // float align
  float* t = (float*)(WtH + ush_elems);          // N*18

  hipMemsetAsync(hist, 0, sizeof(int) * (size_t)S, stream);

  k_hist<<<(E + 255) / 256, 256, 0, stream>>>(dst, et, hist, E);

  int NB = (S + 1023) / 1024;
  k_scan_local<<<NB, 256, 0, stream>>>(hist, offs, blksum, S);
  k_scan_blk<<<1, 512, 0, stream>>>(blksum, blkoff, NB);
  k_scan_add<<<NB, 256, 0, stream>>>(offs, blkoff, S);

  k_scatter_idx<<<(E + 255) / 256, 256, 0, stream>>>(src, dst, et, hist, offs, ei2, E);

  k_wsplit<<<1152, 128, 0, stream>>>(W1, Wr1, WtH, WtL);

  k_gemm_dense<<<(N + 63) / 64, 256, 0, stream>>>(x, WtH, WtL, Y, N);

  k_hgather<<<(N + 3) / 4, 256, 0, stream>>>(offs, hist, ei2, Y, b1, W2, Wr2, t, N);

  k_out2<<<(N + 31) / 32, 256, 0, stream>>>(offs, hist, ei2, t, b2, out, N);
}